// Round 4
// 297.371 us; speedup vs baseline: 1.4565x; 1.4565x over previous
//
#include <hip/hip_runtime.h>
#include <cstdint>

#define TPB 256

static constexpr float INV_SQRT_FAN = 0.08838834764831845f; // 1/sqrt(128)
static constexpr float INV_SQRT3_C  = 0.5773502691896258f;  // 1/sqrt(3)

typedef _Float16 f16x4v __attribute__((ext_vector_type(4)));
typedef float f32x4 __attribute__((ext_vector_type(4)));

// Prep output: f16 weights, K-contiguous (transposed):
//   [0,16384)     W0T: u16[n*128+k] = f16(W0[k*128+n])   n,k in [0,128)
//   [16384,24576) W1T: u16[o*128+k] = f16(W1[k*64+o])    o in [0,64), k in [0,128)
__device__ __align__(16) uint16_t g_wf[24576];

__device__ __forceinline__ uint16_t f2h(float f) {
  union { _Float16 h; uint16_t u; } cv;
  cv.h = (_Float16)f;   // RNE
  return cv.u;
}
__device__ __forceinline__ uint32_t pk2(float a, float b) {
  return (uint32_t)f2h(a) | ((uint32_t)f2h(b) << 16);
}

__global__ void prep_kernel(const float* __restrict__ W0,
                            const float* __restrict__ W1) {
  int id = blockIdx.x * TPB + threadIdx.x;  // [0, 24576)
  if (id < 16384) {
    int k = id >> 7, n = id & 127;          // coalesced read of W0[k][n]
    g_wf[n * 128 + k] = f2h(W0[id]);
  } else {
    int i2 = id - 16384;
    int k = i2 >> 6, o = i2 & 63;           // coalesced read of W1[k][o]
    g_wf[16384 + o * 128 + k] = f2h(W1[i2]);
  }
}

// CDNA1-era shape with fully documented, unambiguous fragment layout:
//   A: lane l holds A[row=l%16][k=4*(l/16)+e], e=0..3 (contiguous 4)
//   B: lane l holds B[k=4*(l/16)+e][col=l%16]
//   D: lane l holds D[row=4*(l/16)+j][col=l%16]
#define MFMA16H(a, b, c) __builtin_amdgcn_mfma_f32_16x16x16f16((a), (b), (c), 0, 0, 0)

// Minimal-delta MFMA port of the verified VALU kernel (f16 variant):
//   - identical tp staging ([r][m][k] linear, 16 rows/block), f16 products
//   - matmul via mfma_f32_16x16x16_f16; raw dot products spilled f32 to LDS
//   - identical epilogue/store to the verified kernel, reading s/v from LDS
__global__ __launch_bounds__(256, 4) void tplg_mfma(
    const float* __restrict__ x, const float* __restrict__ y,
    const float* __restrict__ b0, float* __restrict__ out) {
  // LDS u16 map:
  //   [0,8192)       tp   [16 rows][4 m][128 k] f16 (16KB)
  //   [8192,12288)   s_stage f32 [16][128] (8KB)
  //   [12288,18432)  v_stage f32 [16][192] (12KB), index o*3+i
  // epilogue aliases (after pre-load + barrier):
  //   gatep = f32 [0,1024)   (over dead tp)
  //   stg   = f32 [1024,5120) (over dead tp + dead s_stage)
  __shared__ uint16_t lds16[18432];
  float* ldsf = (float*)lds16;
  float* s_stage = ldsf + 4096;
  float* v_stage = ldsf + 6144;

  const int t = threadIdx.x;
  const long rowBase = (long)blockIdx.x * 16;

  // ---- stage tp (16 rows), f16, layout [r][m][k] k-contiguous (verbatim) ----
  {
    const int u = t & 15;   // column slice [4u, 4u+4)
    const int r = t >> 4;   // row
    const float* xr = x + (rowBase + r) * 256;
    const float4 x0 = *(const float4*)(xr + 4 * u);
    const float4 aa = *(const float4*)(xr + 64 + 12 * u);
    const float4 bb = *(const float4*)(xr + 64 + 12 * u + 4);
    const float4 cc = *(const float4*)(xr + 64 + 12 * u + 8);
    const float4 yv = *(const float4*)(y + (rowBase + r) * 4);
    const float y0 = yv.x, y1 = yv.y, y2 = yv.z, y3 = yv.w;
    const float t0x = aa.x, t0y = aa.y, t0z = aa.z;
    const float t1x = aa.w, t1y = bb.x, t1z = bb.y;
    const float t2x = bb.z, t2y = bb.w, t2z = cc.x;
    const float t3x = cc.y, t3y = cc.z, t3z = cc.w;
    const int c0 = 4 * u;
    const int base = r * 512;  // this row's tp block
    // m=0: tp0. low half k=c0..c0+3 = x0*y0
    *(uint2*)(lds16 + base + c0) =
        make_uint2(pk2(x0.x * y0, x0.y * y0), pk2(x0.z * y0, x0.w * y0));
    // m=0 high half k=64+c0.. = dot(x1[c], y1)*inv_sqrt3
    const float d0 = (t0x * y1 + t0y * y2 + t0z * y3) * INV_SQRT3_C;
    const float d1 = (t1x * y1 + t1y * y2 + t1z * y3) * INV_SQRT3_C;
    const float d2 = (t2x * y1 + t2y * y2 + t2z * y3) * INV_SQRT3_C;
    const float d3 = (t3x * y1 + t3y * y2 + t3z * y3) * INV_SQRT3_C;
    *(uint2*)(lds16 + base + 64 + c0) = make_uint2(pk2(d0, d1), pk2(d2, d3));
    // m=1..3: tp1_i low = x0*y1[i]; high = x1[c][i]*y0
    *(uint2*)(lds16 + base + 128 + c0) =
        make_uint2(pk2(x0.x * y1, x0.y * y1), pk2(x0.z * y1, x0.w * y1));
    *(uint2*)(lds16 + base + 128 + 64 + c0) =
        make_uint2(pk2(t0x * y0, t1x * y0), pk2(t2x * y0, t3x * y0));
    *(uint2*)(lds16 + base + 256 + c0) =
        make_uint2(pk2(x0.x * y2, x0.y * y2), pk2(x0.z * y2, x0.w * y2));
    *(uint2*)(lds16 + base + 256 + 64 + c0) =
        make_uint2(pk2(t0y * y0, t1y * y0), pk2(t2y * y0, t3y * y0));
    *(uint2*)(lds16 + base + 384 + c0) =
        make_uint2(pk2(x0.x * y3, x0.y * y3), pk2(x0.z * y3, x0.w * y3));
    *(uint2*)(lds16 + base + 384 + 64 + c0) =
        make_uint2(pk2(t0z * y0, t1z * y0), pk2(t2z * y0, t3z * y0));
  }
  __syncthreads();

  // ---- MFMA compute: 4 waves ----
  // wave 0: S cols 0-63; wave 1: S cols 64-127; wave 2: v o in [0,32); wave 3: v o in [32,64)
  {
    const int wave = t >> 6;
    const int lane = t & 63;
    const int g = lane >> 4;   // k-subchunk group / D row group
    const int q = lane & 15;   // A row / B col
    const f32x4 zf = {0.f, 0.f, 0.f, 0.f};

    if (wave < 2) {
      const int nb = wave * 64;
      f32x4 p[4] = {zf, zf, zf, zf};
      const uint16_t* tpr = lds16 + q * 512;  // tp0 row q (m=0)
      #pragma unroll
      for (int m2 = 0; m2 < 8; ++m2) {        // K chunk [16*m2, 16*m2+16)
        const f16x4v a = *(const f16x4v*)(tpr + m2 * 16 + g * 4);
        #pragma unroll
        for (int nt = 0; nt < 4; ++nt) {
          const f16x4v b =
              *(const f16x4v*)(g_wf + (nb + nt * 16 + q) * 128 + m2 * 16 + g * 4);
          p[nt] = MFMA16H(a, b, p[nt]);
        }
      }
      #pragma unroll
      for (int nt = 0; nt < 4; ++nt)
        #pragma unroll
        for (int j = 0; j < 4; ++j)
          s_stage[(g * 4 + j) * 128 + nb + nt * 16 + q] = p[nt][j];
    } else {
      const int ob = (wave - 2) * 32;
      f32x4 acc[2][3] = {{zf, zf, zf}, {zf, zf, zf}};
      #pragma unroll
      for (int m2 = 0; m2 < 8; ++m2) {
        f16x4v av[3];
        #pragma unroll
        for (int i = 0; i < 3; ++i)
          av[i] = *(const f16x4v*)(lds16 + q * 512 + (1 + i) * 128 + m2 * 16 + g * 4);
        #pragma unroll
        for (int nt = 0; nt < 2; ++nt) {
          const f16x4v b = *(const f16x4v*)(g_wf + 16384 +
                                            (ob + nt * 16 + q) * 128 + m2 * 16 + g * 4);
          #pragma unroll
          for (int i = 0; i < 3; ++i) acc[nt][i] = MFMA16H(av[i], b, acc[nt][i]);
        }
      }
      #pragma unroll
      for (int nt = 0; nt < 2; ++nt)
        #pragma unroll
        for (int i = 0; i < 3; ++i)
          #pragma unroll
          for (int j = 0; j < 4; ++j)
            v_stage[(g * 4 + j) * 192 + (ob + nt * 16 + q) * 3 + i] = acc[nt][i][j];
    }
  }
  __syncthreads();

  // ---- pre-load epilogue operands (thread = (row r, col-worker w)) ----
  const int r = t >> 4, w = t & 15;
  float sacc[8], vacc[12];
  #pragma unroll
  for (int n = 0; n < 8; ++n) sacc[n] = s_stage[r * 128 + 8 * w + n];
  #pragma unroll
  for (int o4 = 0; o4 < 4; ++o4)
    #pragma unroll
    for (int i = 0; i < 3; ++i)
      vacc[o4 * 3 + i] = v_stage[r * 192 + (4 * w + o4) * 3 + i];
  __syncthreads();  // everyone holds s/v in regs; alias regions now

  // ---- epilogue (verbatim from verified kernel) ----
  float* gatep = ldsf;          // 16 x 64 gates (over dead tp)
  float* stg   = ldsf + 1024;   // 16 x 256 out-staging
  if (w < 8) {
    #pragma unroll
    for (int n = 0; n < 8; ++n) {
      const int col = 8 * w + n;  // gate col [0,64)
      const float s = sacc[n] * INV_SQRT_FAN + b0[col];
      gatep[r * 64 + col] = __builtin_amdgcn_rcpf(1.0f + __expf(-s));
    }
  } else {
    #pragma unroll
    for (int n = 0; n < 8; ++n) {
      const int col = 8 * w + n;  // scalar col [64,128)
      const float s = sacc[n] * INV_SQRT_FAN + b0[col];
      const float u3 = s * s * s;
      const float ua = 0.7978845608028654f * (s + 0.044715f * u3);
      const float e = __expf(2.0f * ua);
      const float th = 1.0f - 2.0f * __builtin_amdgcn_rcpf(e + 1.0f);
      stg[r * 256 + (col - 64)] = 0.5f * s * (1.0f + th);
    }
  }
  __syncthreads();
  #pragma unroll
  for (int o4 = 0; o4 < 4; ++o4) {
    const int o = 4 * w + o4;
    const float gq = gatep[r * 64 + o];
    #pragma unroll
    for (int i = 0; i < 3; ++i) {
      stg[r * 256 + 64 + o * 3 + i] = gq * vacc[o4 * 3 + i] * INV_SQRT_FAN;
    }
  }
  __syncthreads();

  // ---- coalesced store: 16 rows x 256 f32 = 1024 float4 ----
  const float4* s4 = (const float4*)stg;
  float4* o4p = (float4*)(out + rowBase * 256);
  #pragma unroll
  for (int i = 0; i < 4; ++i) o4p[i * 256 + t] = s4[i * 256 + t];
}

extern "C" void kernel_launch(void* const* d_in, const int* in_sizes, int n_in,
                              void* d_out, int out_size, void* d_ws, size_t ws_size,
                              hipStream_t stream) {
  const float* x  = (const float*)d_in[0];
  const float* y  = (const float*)d_in[1];
  const float* W0 = (const float*)d_in[2];
  const float* b0 = (const float*)d_in[3];
  const float* W1 = (const float*)d_in[4];
  float* out = (float*)d_out;
  (void)d_ws; (void)ws_size;

  const int rows = in_sizes[0] / 256;  // 131072
  prep_kernel<<<24576 / TPB, TPB, 0, stream>>>(W0, W1);
  tplg_mfma<<<rows / 16, TPB, 0, stream>>>(x, y, b0, out);
}